// Round 5
// baseline (36.996 us; speedup 1.0000x reference)
//
#include <hip/hip_runtime.h>
#include <cmath>

typedef __attribute__((ext_vector_type(8))) short short8;
typedef __attribute__((ext_vector_type(4))) float f32x4;

#define NB 32
#define MU_OUT_SZ (NB*100*64)   // 204800
#define LDAP 56                 // shorts per (h,w) row in LDS (112 B padded)

// ws byte offsets
#define WS_WF 0                 // bf16 frags [25][2][4][64][8] = 204800 B
#define WS_G  204800            // f32 [32][100][100] = 1280000 B
#define WS_DV 1484800           // f32 [32][100][64]  = 819200 B

__device__ inline unsigned short f2bf(float f) {
  unsigned u = __builtin_bit_cast(unsigned, f);
  u += 0x7fffu + ((u >> 16) & 1u);
  return (unsigned short)(u >> 16);
}

// ---------------- prepW: pack W and (W^2 + softplus) into MFMA B-frag order ----------------
__global__ __launch_bounds__(256) void prepW(
    const float* __restrict__ w_mu, const float* __restrict__ w_sigma,
    unsigned short* __restrict__ wf) {
  const int wid = blockIdx.x * 256 + threadIdx.x;   // 0..12799
  const int kind = wid >= 6400 ? 1 : 0;             // 0: W, 1: W^2 + sp
  const int fid = kind ? wid - 6400 : wid;
  const int ij = fid >> 8;                          // 0..24
  const int rest = fid & 255;
  const int n = rest >> 6, l = rest & 63;
  const int col = n * 16 + (l & 15);                // output channel k
  const int m0 = ij * 32 + (l >> 4) * 8;            // K-row base
  const float sp = log1pf(expf(w_sigma[col]));
  unsigned short v[8];
#pragma unroll
  for (int i = 0; i < 8; ++i) {
    float wv = w_mu[(m0 + i) * 64 + col];
    float x = kind ? (wv * wv + sp) : wv;
    v[i] = f2bf(x);
  }
  uint4 pk;
  pk.x = v[0] | ((unsigned)v[1] << 16);
  pk.y = v[2] | ((unsigned)v[3] << 16);
  pk.z = v[4] | ((unsigned)v[5] << 16);
  pk.w = v[6] | ((unsigned)v[7] << 16);
  *(uint4*)(wf + (size_t)((ij * 8 + kind * 4 + n) * 64 + l) * 8) = pk;
}

// ---------------- gemm: G = Mp*Mp^T, mu_out = Mp*W, dv = Sp*(W^2+sp) ----------------
__global__ __launch_bounds__(256) void gemm(
    const float* __restrict__ mu_in, const float* __restrict__ Sigma_in,
    const unsigned short* __restrict__ wf,
    float* __restrict__ G, float* __restrict__ dv, float* __restrict__ out) {
  __shared__ unsigned short mu_sh[196 * LDAP];
  __shared__ unsigned short sd_sh[196 * LDAP];
  const int r = blockIdx.x;            // row tile 0..6 (p rows 16r..16r+15)
  const int b = blockIdx.y;
  const int t = threadIdx.x, l = t & 63, w = t >> 6;

  // stage mu[b] and diag(Sigma[b]) as bf16, padded rows
  const float4* mu4 = (const float4*)(mu_in + (size_t)b * 6272);
  for (int f = t; f < 1568; f += 256) {
    const float4 v = mu4[f];
    const int row = f >> 3, c = (f & 7) * 4;
    ushort4 pv;
    pv.x = f2bf(v.x); pv.y = f2bf(v.y); pv.z = f2bf(v.z); pv.w = f2bf(v.w);
    *(ushort4*)(mu_sh + row * LDAP + c) = pv;
    const float4 s = *(const float4*)(Sigma_in +
        ((size_t)(b * 196 + row) * 196 + row) * 32 + c);
    ushort4 ps;
    ps.x = f2bf(s.x); ps.y = f2bf(s.y); ps.z = f2bf(s.z); ps.w = f2bf(s.w);
    *(ushort4*)(sd_sh + row * LDAP + c) = ps;
  }
  __syncthreads();

  const int laneP = l & 15, g16 = (l >> 4) * 8;
  int pA = r * 16 + laneP; if (pA > 99) pA = 99;
  const int baseA = ((pA / 10) * 14 + (pA % 10)) * LDAP + g16;
  const int prow0 = (l >> 4) * 4;

  if (w <= 1) {
    // G column tiles: w0 -> 0..3, w1 -> 4..7 (tile 7 is OOB, guarded at store)
    const int c0 = w * 4;
    int baseB[4];
#pragma unroll
    for (int i = 0; i < 4; ++i) {
      int col = (c0 + i) * 16 + laneP;
      int pc = col > 99 ? 99 : col;
      baseB[i] = ((pc / 10) * 14 + (pc % 10)) * LDAP + g16;
    }
    f32x4 acc[4] = {};
#pragma unroll
    for (int ij = 0; ij < 25; ++ij) {
      const int off = ((ij / 5) * 14 + (ij % 5)) * LDAP;
      const short8 fA = *(const short8*)(mu_sh + baseA + off);
#pragma unroll
      for (int i = 0; i < 4; ++i) {
        const short8 fB = *(const short8*)(mu_sh + baseB[i] + off);
        acc[i] = __builtin_amdgcn_mfma_f32_16x16x32_bf16(fA, fB, acc[i], 0, 0, 0);
      }
    }
    float* Gb = G + (size_t)b * 10000;
#pragma unroll
    for (int i = 0; i < 4; ++i) {
      const int col = (c0 + i) * 16 + laneP;
      if (col < 100) {
#pragma unroll
        for (int j = 0; j < 4; ++j) {
          const int row = r * 16 + prow0 + j;
          if (row < 100) Gb[row * 100 + col] = acc[i][j];
        }
      }
    }
  } else if (w == 2) {
    // mu_out: 4 k-tiles
    f32x4 acc[4] = {};
#pragma unroll
    for (int ij = 0; ij < 25; ++ij) {
      const int off = ((ij / 5) * 14 + (ij % 5)) * LDAP;
      const short8 fA = *(const short8*)(mu_sh + baseA + off);
#pragma unroll
      for (int n = 0; n < 4; ++n) {
        const short8 bw = *(const short8*)(wf + (size_t)((ij * 8 + n) * 64 + l) * 8);
        acc[n] = __builtin_amdgcn_mfma_f32_16x16x32_bf16(fA, bw, acc[n], 0, 0, 0);
      }
    }
    float* mo = out + (size_t)b * 6400;
#pragma unroll
    for (int n = 0; n < 4; ++n) {
      const int k = n * 16 + laneP;
#pragma unroll
      for (int j = 0; j < 4; ++j) {
        const int p = r * 16 + prow0 + j;
        if (p < 100) mo[p * 64 + k] = acc[n][j];
      }
    }
  } else {
    // dv: 4 k-tiles, A = Sigma-diag patches, B = W^2 + sp
    f32x4 acc[4] = {};
#pragma unroll
    for (int ij = 0; ij < 25; ++ij) {
      const int off = ((ij / 5) * 14 + (ij % 5)) * LDAP;
      const short8 fS = *(const short8*)(sd_sh + baseA + off);
#pragma unroll
      for (int n = 0; n < 4; ++n) {
        const short8 b2 = *(const short8*)(wf + (size_t)((ij * 8 + 4 + n) * 64 + l) * 8);
        acc[n] = __builtin_amdgcn_mfma_f32_16x16x32_bf16(fS, b2, acc[n], 0, 0, 0);
      }
    }
    float* dvb = dv + (size_t)b * 6400;
#pragma unroll
    for (int n = 0; n < 4; ++n) {
      const int k = n * 16 + laneP;
#pragma unroll
      for (int j = 0; j < 4; ++j) {
        const int p = r * 16 + prow0 + j;
        if (p < 100) dvb[p * 64 + k] = acc[n][j];
      }
    }
  }
}

// ---------------- writer: balanced grid-stride stream of Sigma_out ----------------
__global__ __launch_bounds__(256) void writer(
    const float* __restrict__ G, const float* __restrict__ dv,
    const float* __restrict__ w_sigma, float* __restrict__ out) {
  const unsigned tid = blockIdx.x * 256 + threadIdx.x;
  const int k4 = (tid & 15) * 4;       // constant per thread (stride % 16 == 0)
  const float4 wsv = *(const float4*)(w_sigma + k4);
  f32x4 sp4;
  sp4.x = log1pf(expf(wsv.x));
  sp4.y = log1pf(expf(wsv.y));
  sp4.z = log1pf(expf(wsv.z));
  sp4.w = log1pf(expf(wsv.w));
  float* sig = out + MU_OUT_SZ;
  for (unsigned l4 = tid; l4 < 5120000u; l4 += 524288u) {
    const unsigned rr = l4 >> 4;        // = (b*100 + p)*100 + q
    const unsigned q = rr % 100u;
    const unsigned pq = rr / 100u;      // = b*100 + p
    const unsigned p = pq % 100u;
    const float g = G[rr];
    f32x4 v;
    v.x = sp4.x * g; v.y = sp4.y * g; v.z = sp4.z * g; v.w = sp4.w * g;
    if (q == p) {
      const float4 dvv = *(const float4*)(dv + (size_t)pq * 64 + k4);
      v.x += dvv.x; v.y += dvv.y; v.z += dvv.z; v.w += dvv.w;
    }
    v.x = (q == (unsigned)k4)     ? fabsf(v.x) : v.x;
    v.y = (q == (unsigned)k4 + 1) ? fabsf(v.y) : v.y;
    v.z = (q == (unsigned)k4 + 2) ? fabsf(v.z) : v.z;
    v.w = (q == (unsigned)k4 + 3) ? fabsf(v.w) : v.w;
    __builtin_nontemporal_store(v, (f32x4*)(sig + (size_t)l4 * 4));
  }
}

extern "C" void kernel_launch(void* const* d_in, const int* in_sizes, int n_in,
                              void* d_out, int out_size, void* d_ws, size_t ws_size,
                              hipStream_t stream) {
  const float* mu_in    = (const float*)d_in[0];
  const float* Sigma_in = (const float*)d_in[1];
  const float* w_mu     = (const float*)d_in[2];
  const float* w_sigma  = (const float*)d_in[3];
  float* out = (float*)d_out;
  unsigned char* ws = (unsigned char*)d_ws;
  unsigned short* wf = (unsigned short*)(ws + WS_WF);
  float* G  = (float*)(ws + WS_G);
  float* dv = (float*)(ws + WS_DV);

  prepW<<<50, 256, 0, stream>>>(w_mu, w_sigma, wf);
  gemm<<<dim3(7, NB), 256, 0, stream>>>(mu_in, Sigma_in, wf, G, dv, out);
  writer<<<2048, 256, 0, stream>>>(G, dv, w_sigma, out);
}